// Round 13
// baseline (302.344 us; speedup 1.0000x reference)
//
#include <hip/hip_runtime.h>
#include <hip/hip_bf16.h>
#include <string.h>

typedef __hip_bfloat16 bf16;

#define FIN 16
#define H   32
#define PADW 64
#define NB  512
#define BINCAP 4096
#define NPBMAX 200
#define PSTRIDE 65
#define CHUNK 8192
#define SCAN_CHUNK 1024
#define MAXSEG 64

__device__ __forceinline__ float b2f(bf16 v) { return __bfloat162float(v); }

__device__ __forceinline__ float loadf(const void* p, size_t i, int f32) {
    return f32 ? ((const float*)p)[i] : b2f(((const bf16*)p)[i]);
}
__device__ __forceinline__ void storef(void* p, size_t i, float v, int f32) {
    if (f32) ((float*)p)[i] = v;
    else     ((bf16*)p)[i] = __float2bfloat16(v);
}

__device__ __forceinline__ unsigned pack2(float lo, float hi) {
    bf16 a = __float2bfloat16(lo), b = __float2bfloat16(hi);
    unsigned short ua, ub;
    memcpy(&ua, &a, 2); memcpy(&ub, &b, 2);
    return ((unsigned)ub << 16) | (unsigned)ua;
}
__device__ __forceinline__ float f_lo(unsigned u) {
    union { unsigned i; float f; } v; v.i = u << 16; return v.f;
}
__device__ __forceinline__ float f_hi(unsigned u) {
    union { unsigned i; float f; } v; v.i = u & 0xffff0000u; return v.f;
}

// detect dtype + zero pooled/cnt + zero bincur, one block
__global__ void k_init(const void* __restrict__ x, int nelem, int* __restrict__ flag,
                       float* __restrict__ pooled, int poolN, int* __restrict__ bincur) {
    __shared__ int cnt;
    if (threadIdx.x == 0) cnt = 0;
    __syncthreads();
    int bad = 0;
    const bf16* p = (const bf16*)x;
    for (int i = threadIdx.x; i < nelem; i += blockDim.x) {
        float v = b2f(p[i]);
        float a = fabsf(v);
        if (isnan(v) || a > 1024.f || (v != 0.f && a < 1e-20f)) bad++;
    }
    atomicAdd(&cnt, bad);
    for (int i = threadIdx.x; i < poolN; i += blockDim.x) pooled[i] = 0.f;
    for (int i = threadIdx.x; i < NB; i += blockDim.x) bincur[i] = 0;
    __syncthreads();
    if (threadIdx.x == 0) flag[0] = (cnt > 64) ? 1 : 0;
}

// ---------- Tier A2: two-phase binned padded-CSR build ----------

__global__ void __launch_bounds__(1024) k_p1(
        const int* __restrict__ src, const int* __restrict__ dst,
        int* __restrict__ bincur, unsigned* __restrict__ binbuf,
        int E, int npb) {
    __shared__ int hcnt[4][NB];
    __shared__ int hbase[NB];
    __shared__ int scur[NB];
    int tid = threadIdx.x;
    int grp = tid >> 8;
    int e0 = blockIdx.x * CHUNK;
    int nE = E - e0;
    if (nE > CHUNK) nE = CHUNK;
    for (int i = tid; i < 4 * NB; i += blockDim.x) ((int*)hcnt)[i] = 0;
    __syncthreads();
    for (int i = tid; i < nE; i += blockDim.x)
        atomicAdd(&hcnt[grp][dst[e0 + i] / npb], 1);
    __syncthreads();
    for (int i = tid; i < NB; i += blockDim.x) {
        int c = hcnt[0][i] + hcnt[1][i] + hcnt[2][i] + hcnt[3][i];
        hbase[i] = c ? atomicAdd(&bincur[i], c) : 0;
        scur[i] = 0;
    }
    __syncthreads();
    for (int i = tid; i < nE; i += blockDim.x) {
        int d = dst[e0 + i];
        int bin = d / npb;
        int pos = hbase[bin] + atomicAdd(&scur[bin], 1);
        if (pos < BINCAP)
            binbuf[(size_t)bin * BINCAP + pos] =
                ((unsigned)src[e0 + i] << 10) | (unsigned)(d - bin * npb);
    }
}

// build CSR segment in LDS (stride-65), stream out, emit deg/dinv,
// AND compute the layer-1 packed messages xsb for this bin's nodes (fused xw1).
__global__ void __launch_bounds__(256) k_p2x(
        const int* __restrict__ bincur, const unsigned* __restrict__ binbuf,
        const void* __restrict__ x, const void* __restrict__ W1,
        const int* __restrict__ flag,
        int* __restrict__ csr, int* __restrict__ deg, float* __restrict__ dinv,
        unsigned* __restrict__ xsb, int N, int npb) {
    __shared__ int cur[NPBMAX];
    __shared__ int psr[NPBMAX * PSTRIDE];   // ~52 KB
    __shared__ float sW[FIN * H];           // 2 KB
    int f32 = flag[0];
    for (int i = threadIdx.x; i < FIN * H; i += blockDim.x) sW[i] = loadf(W1, i, f32);
    int b = blockIdx.x;
    int base = b * npb;
    int nn = N - base;
    if (nn > npb) nn = npb;
    if (nn < 0) nn = 0;
    for (int i = threadIdx.x; i < nn; i += blockDim.x) cur[i] = 0;
    __syncthreads();
    int cnt = bincur[b];
    if (cnt > BINCAP) cnt = BINCAP;
    const unsigned* buf = binbuf + (size_t)b * BINCAP;
    for (int j = threadIdx.x; j < cnt; j += blockDim.x) {
        unsigned p = buf[j];
        int loc = (int)(p & 1023u);
        int s = (int)(p >> 10);
        int pos = atomicAdd(&cur[loc], 1);
        if (pos < PADW) psr[loc * PSTRIDE + pos] = s;
    }
    __syncthreads();
    int tot = nn * PADW;
    for (int idx = threadIdx.x; idx < tot; idx += blockDim.x) {
        int i = idx >> 6, p = idx & 63;
        csr[((size_t)(base + i) << 6) + p] = psr[i * PSTRIDE + p];
    }
    // fused layer-1: xsb[n] = pack2((x[n] @ W1) * dinv[n])
    for (int i = threadIdx.x; i < nn; i += blockDim.x) {
        int dg = cur[i];
        int n = base + i;
        float dv = rsqrtf((float)dg + 1.0f);
        deg[n] = dg;
        dinv[n] = dv;
        float xr[FIN];
#pragma unroll
        for (int k = 0; k < FIN; k++) xr[k] = loadf(x, (size_t)n * FIN + k, f32);
#pragma unroll
        for (int f2 = 0; f2 < H / 2; f2++) {
            float s0 = 0.f, s1 = 0.f;
#pragma unroll
            for (int k = 0; k < FIN; k++) {
                s0 += xr[k] * sW[k * H + 2 * f2];
                s1 += xr[k] * sW[k * H + 2 * f2 + 1];
            }
            xsb[(size_t)n * (H / 2) + f2] = pack2(s0 * dv, s1 * dv);
        }
    }
}

// ---------- Tier A: direct padded CSR (fallback build) ----------

__global__ void k_fillp(const int* __restrict__ src, const int* __restrict__ dst,
                        int* __restrict__ cursor, int* __restrict__ csr, int E) {
    int e = blockIdx.x * blockDim.x + threadIdx.x;
    if (e >= E) return;
    int d = dst[e];
    int pos = atomicAdd(&cursor[d], 1);
    if (pos < PADW) csr[((size_t)d << 6) + pos] = src[e];
}

__global__ void k_dinvi(const int* __restrict__ deg, float* __restrict__ dinv, int N) {
    int t = blockIdx.x * blockDim.x + threadIdx.x;
    if (t < N) dinv[t] = rsqrtf((float)deg[t] + 1.0f);
}

// bf16-table gather: 16 lanes/node, lane j owns packed pair (2j,2j+1).
__global__ void k_gatherpb(const int* __restrict__ deg, const int* __restrict__ csr,
                           const float* __restrict__ dinv, const unsigned* __restrict__ xsb,
                           float2* __restrict__ agg, int N) {
    int t = blockIdx.x * blockDim.x + threadIdx.x;
    int d = t >> 4, j = t & 15;
    if (d >= N) return;
    int len = deg[d];
    if (len > PADW) len = PADW;
    const int* lst = csr + ((size_t)d << 6);
    unsigned u = xsb[(size_t)d * 16 + j];      // self-loop
    float a0 = f_lo(u), a1 = f_hi(u);
    float b0 = 0.f, b1 = 0.f;
    int k = 0;
    for (; k + 1 < len; k += 2) {
        int s0 = lst[k], s1 = lst[k + 1];
        unsigned u0 = xsb[(size_t)s0 * 16 + j];
        unsigned u1 = xsb[(size_t)s1 * 16 + j];
        a0 += f_lo(u0); a1 += f_hi(u0);
        b0 += f_lo(u1); b1 += f_hi(u1);
    }
    if (k < len) {
        unsigned u2 = xsb[(size_t)lst[k] * 16 + j];
        a0 += f_lo(u2); a1 += f_hi(u2);
    }
    float dv = dinv[d];
    agg[(size_t)d * 16 + j] = make_float2((a0 + b0) * dv, (a1 + b1) * dv);
}

// ---------- wave-cooperative dense kernels (16 lanes/node) ----------

__global__ void __launch_bounds__(256) k_xw1v(
        const void* __restrict__ x, const void* __restrict__ W1,
        const float* __restrict__ dinv, const int* __restrict__ flag,
        unsigned* __restrict__ xsb, int N) {
    __shared__ float sW[FIN * H];
    __shared__ float sxx[16 * 17];
    int f32 = flag[0];
    for (int i = threadIdx.x; i < FIN * H; i += blockDim.x) sW[i] = loadf(W1, i, f32);
    __syncthreads();
    int t = blockIdx.x * blockDim.x + threadIdx.x;
    int n = t >> 4, j = t & 15, g = threadIdx.x >> 4;
    if (n < N) sxx[g * 17 + j] = loadf(x, (size_t)n * FIN + j, f32);
    __syncthreads();
    if (n >= N) return;
    float dv = dinv[n];
    float s0 = 0.f, s1 = 0.f;
    const float* xp = &sxx[g * 17];
#pragma unroll
    for (int i = 0; i < FIN; i++) {
        float xv = xp[i];
        s0 += xv * sW[i * H + 2 * j];
        s1 += xv * sW[i * H + 2 * j + 1];
    }
    xsb[(size_t)n * 16 + j] = pack2(s0 * dv, s1 * dv);
}

__global__ void __launch_bounds__(256) k_h1xw2v(
        const void* __restrict__ W2, const void* __restrict__ b1,
        const float* __restrict__ dinv, const int* __restrict__ flag,
        const float2* __restrict__ aggv, unsigned* __restrict__ xsb2, int N) {
    __shared__ float sW[H * H];
    __shared__ float sb[H];
    __shared__ float shh[16 * 33];
    int f32 = flag[0];
    for (int i = threadIdx.x; i < H * H; i += blockDim.x) sW[i] = loadf(W2, i, f32);
    if (threadIdx.x < H) sb[threadIdx.x] = loadf(b1, threadIdx.x, f32);
    __syncthreads();
    int t = blockIdx.x * blockDim.x + threadIdx.x;
    int n = t >> 4, j = t & 15, g = threadIdx.x >> 4;
    if (n < N) {
        float2 a = aggv[(size_t)n * 16 + j];
        float v0 = a.x + sb[2 * j], v1 = a.y + sb[2 * j + 1];
        shh[g * 33 + 2 * j]     = v0 > 0.f ? v0 : 0.f;
        shh[g * 33 + 2 * j + 1] = v1 > 0.f ? v1 : 0.f;
    }
    __syncthreads();
    if (n >= N) return;
    float dv = dinv[n];
    float s0 = 0.f, s1 = 0.f;
    const float* hp = &shh[g * 33];
#pragma unroll
    for (int i = 0; i < H; i++) {
        float hv = hp[i];
        s0 += hv * sW[i * H + 2 * j];
        s1 += hv * sW[i * H + 2 * j + 1];
    }
    xsb2[(size_t)n * 16 + j] = pack2(s0 * dv, s1 * dv);
}

// h = agg2 + b2; hb = bf16(h); gb = bf16(h @ Wbil)   (16 lanes/node)
__global__ void __launch_bounds__(256) k_hb(
        const void* __restrict__ b2v, const void* __restrict__ Wbil,
        const int* __restrict__ flag, const float2* __restrict__ aggv,
        unsigned* __restrict__ hb32, unsigned* __restrict__ gb32, int N) {
    __shared__ float sW[H * H];
    __shared__ float sb[H];
    __shared__ float shh[16 * 33];
    int f32 = flag[0];
    for (int i = threadIdx.x; i < H * H; i += blockDim.x) sW[i] = loadf(Wbil, i, f32);
    if (threadIdx.x < H) sb[threadIdx.x] = loadf(b2v, threadIdx.x, f32);
    __syncthreads();
    int t = blockIdx.x * blockDim.x + threadIdx.x;
    int n = t >> 4, j = t & 15, g = threadIdx.x >> 4;
    if (n < N) {
        float2 a = aggv[(size_t)n * 16 + j];
        float v0 = a.x + sb[2 * j], v1 = a.y + sb[2 * j + 1];
        shh[g * 33 + 2 * j]     = v0;
        shh[g * 33 + 2 * j + 1] = v1;
        hb32[(size_t)n * 16 + j] = pack2(v0, v1);
    }
    __syncthreads();
    if (n >= N) return;
    float s0 = 0.f, s1 = 0.f;
    const float* hp = &shh[g * 33];
#pragma unroll
    for (int i = 0; i < H; i++) {
        float hv = hp[i];
        s0 += hv * sW[i * H + 2 * j];
        s1 += hv * sW[i * H + 2 * j + 1];
    }
    gb32[(size_t)n * 16 + j] = pack2(s0, s1);
}

// parallel segmented mean-pool
__global__ void __launch_bounds__(256) k_pool(
        const void* __restrict__ b2v, const int* __restrict__ batch,
        const int* __restrict__ flag, const float* __restrict__ aggB,
        float* __restrict__ pooled, float* __restrict__ cnt, int N) {
    __shared__ float sb[H];
    __shared__ int   sg[256];
    __shared__ float spool[MAXSEG * H];
    __shared__ float scnt[MAXSEG];
    int f32 = flag[0];
    if (threadIdx.x < H) sb[threadIdx.x] = loadf(b2v, threadIdx.x, f32);
    int blk0 = blockIdx.x * blockDim.x;
    int nvalid = N - blk0;
    if (nvalid > (int)blockDim.x) nvalid = blockDim.x;
    if ((int)threadIdx.x < nvalid) sg[threadIdx.x] = batch[blk0 + threadIdx.x];
    __syncthreads();
    int g0 = sg[0];
    int nseg = sg[nvalid - 1] - g0 + 1;
    int f = threadIdx.x & 31, k = threadIdx.x >> 5;
    if (nseg <= MAXSEG) {
        for (int i = threadIdx.x; i < nseg * H; i += blockDim.x) spool[i] = 0.f;
        for (int i = threadIdx.x; i < nseg; i += blockDim.x) scnt[i] = 0.f;
        __syncthreads();
        for (int r = k; r < nvalid; r += 8) {
            float v = aggB[(size_t)(blk0 + r) * H + f] + sb[f];
            int gl = sg[r] - g0;
            atomicAdd(&spool[gl * H + f], v);
            if (f == 0) atomicAdd(&scnt[gl], 1.f);
        }
        __syncthreads();
        for (int i = threadIdx.x; i < nseg * H; i += blockDim.x)
            atomicAdd(&pooled[(size_t)(g0 + (i >> 5)) * H + (i & 31)], spool[i]);
        for (int i = threadIdx.x; i < nseg; i += blockDim.x)
            atomicAdd(&cnt[g0 + i], scnt[i]);
    } else {
        for (int r = k; r < nvalid; r += 8) {
            float v = aggB[(size_t)(blk0 + r) * H + f] + sb[f];
            atomicAdd(&pooled[(size_t)sg[r] * H + f], v);
            if (f == 0) atomicAdd(&cnt[sg[r]], 1.f);
        }
    }
}

// ---------- Tier B: compact CSR via scans (fp32 path) ----------

__global__ void k_degi(const int* __restrict__ dst, int* __restrict__ deg, int E) {
    int t = blockIdx.x * blockDim.x + threadIdx.x;
    if (t < E) atomicAdd(&deg[dst[t]], 1);
}

__global__ void k_scan1(const int* __restrict__ deg, int* __restrict__ partials, int N) {
    __shared__ int sd[256];
    int base = blockIdx.x * SCAN_CHUNK + threadIdx.x * 4;
    int s = 0;
#pragma unroll
    for (int k = 0; k < 4; k++) { int i = base + k; s += (i < N) ? deg[i] : 0; }
    sd[threadIdx.x] = s;
    __syncthreads();
    for (int off = 128; off > 0; off >>= 1) {
        if (threadIdx.x < off) sd[threadIdx.x] += sd[threadIdx.x + off];
        __syncthreads();
    }
    if (threadIdx.x == 0) partials[blockIdx.x] = sd[0];
}

__global__ void k_scan2(const int* __restrict__ partials, int* __restrict__ chunk_off, int B1) {
    __shared__ int sd[256];
    int t = threadIdx.x;
    int lv[4];
    int s = 0;
#pragma unroll
    for (int k = 0; k < 4; k++) { int i = t * 4 + k; lv[k] = (i < B1) ? partials[i] : 0; s += lv[k]; }
    sd[t] = s;
    __syncthreads();
    int inc = s;
    for (int off = 1; off < 256; off <<= 1) {
        int v = (t >= off) ? sd[t - off] : 0;
        __syncthreads();
        sd[t] += v;
        __syncthreads();
    }
    int run = sd[t] - inc;
#pragma unroll
    for (int k = 0; k < 4; k++) { int i = t * 4 + k; if (i < B1) chunk_off[i] = run; run += lv[k]; }
    if (t == 255) chunk_off[B1] = run;
}

__global__ void k_scan3(const int* __restrict__ deg, const int* __restrict__ chunk_off,
                        int* __restrict__ row_ptr, int* __restrict__ cursor,
                        int N, int E) {
    __shared__ int sd[256];
    int t = threadIdx.x;
    int base = blockIdx.x * SCAN_CHUNK + t * 4;
    int lv[4];
    int s = 0;
#pragma unroll
    for (int k = 0; k < 4; k++) { int i = base + k; lv[k] = (i < N) ? deg[i] : 0; s += lv[k]; }
    sd[t] = s;
    __syncthreads();
    int inc = s;
    for (int off = 1; off < 256; off <<= 1) {
        int v = (t >= off) ? sd[t - off] : 0;
        __syncthreads();
        sd[t] += v;
        __syncthreads();
    }
    int run = chunk_off[blockIdx.x] + sd[t] - inc;
#pragma unroll
    for (int k = 0; k < 4; k++) {
        int i = base + k;
        if (i < N) { row_ptr[i] = run; cursor[i] = run; }
        run += lv[k];
    }
    if (blockIdx.x == 0 && t == 0) row_ptr[N] = E;
}

__global__ void k_fill(const int* __restrict__ src, const int* __restrict__ dst,
                       int* __restrict__ cursor, int* __restrict__ csr, int E) {
    int e = blockIdx.x * blockDim.x + threadIdx.x;
    if (e >= E) return;
    int pos = atomicAdd(&cursor[dst[e]], 1);
    csr[pos] = src[e];
}

__global__ void k_gather(const int* __restrict__ row_ptr, const int* __restrict__ csr,
                         const float* __restrict__ dinv, const float* __restrict__ xs,
                         float* __restrict__ agg, int N) {
    int t = blockIdx.x * blockDim.x + threadIdx.x;
    int d = t >> 5, f = t & 31;
    if (d >= N) return;
    int beg = row_ptr[d], end = row_ptr[d + 1];
    float acc  = xs[(size_t)d * H + f];
    float acc2 = 0.f;
    int j = beg;
    for (; j + 1 < end; j += 2) {
        int s0 = csr[j], s1 = csr[j + 1];
        acc  += xs[(size_t)s0 * H + f];
        acc2 += xs[(size_t)s1 * H + f];
    }
    if (j < end) acc += xs[(size_t)csr[j] * H + f];
    agg[(size_t)d * H + f] = (acc + acc2) * dinv[d];
}

__global__ void k_xw1n(const void* __restrict__ x, const void* __restrict__ W1,
                       const float* __restrict__ dinv, const int* __restrict__ flag,
                       float* __restrict__ xs, int N) {
    __shared__ float sW[FIN * H];
    int f32 = flag[0];
    for (int i = threadIdx.x; i < FIN * H; i += blockDim.x) sW[i] = loadf(W1, i, f32);
    __syncthreads();
    int n = blockIdx.x * blockDim.x + threadIdx.x;
    if (n >= N) return;
    float xr[FIN];
#pragma unroll
    for (int i = 0; i < FIN; i++) xr[i] = loadf(x, (size_t)n * FIN + i, f32);
    float dv = dinv[n];
#pragma unroll
    for (int f = 0; f < H; f++) {
        float s = 0.f;
#pragma unroll
        for (int i = 0; i < FIN; i++) s += xr[i] * sW[i * H + f];
        xs[(size_t)n * H + f] = s * dv;
    }
}

__global__ void k_h1xw2n(const void* __restrict__ W2, const void* __restrict__ b1,
                         const float* __restrict__ dinv, const int* __restrict__ flag,
                         const float* __restrict__ agg, float* __restrict__ xs2, int N) {
    __shared__ float sW[H * H];
    __shared__ float sb[H];
    int f32 = flag[0];
    for (int i = threadIdx.x; i < H * H; i += blockDim.x) sW[i] = loadf(W2, i, f32);
    if (threadIdx.x < H) sb[threadIdx.x] = loadf(b1, threadIdx.x, f32);
    __syncthreads();
    int n = blockIdx.x * blockDim.x + threadIdx.x;
    if (n >= N) return;
    float hr[H];
#pragma unroll
    for (int f = 0; f < H; f++) {
        float v = agg[(size_t)n * H + f] + sb[f];
        hr[f] = v > 0.f ? v : 0.f;
    }
    float dv = dinv[n];
#pragma unroll
    for (int f = 0; f < H; f++) {
        float s = 0.f;
#pragma unroll
        for (int i = 0; i < H; i++) s += hr[i] * sW[i * H + f];
        xs2[(size_t)n * H + f] = s * dv;
    }
}

// ---------- Tier C fallback: scatter path ----------

__global__ void k_degf(const int* __restrict__ dst, float* __restrict__ deg, int E) {
    int t = blockIdx.x * blockDim.x + threadIdx.x;
    if (t < E) atomicAdd(&deg[dst[t]], 1.0f);
}
__global__ void k_dinvf(float* __restrict__ deg, int N) {
    int t = blockIdx.x * blockDim.x + threadIdx.x;
    if (t < N) deg[t] = rsqrtf(deg[t] + 1.0f);
}
__global__ void k_xw1o(const void* __restrict__ x, const void* __restrict__ W1,
                       const float* __restrict__ dinv, const int* __restrict__ flag,
                       float* __restrict__ xw, float* __restrict__ agg, int N) {
    __shared__ float sW[FIN * H];
    int f32 = flag[0];
    for (int i = threadIdx.x; i < FIN * H; i += blockDim.x) sW[i] = loadf(W1, i, f32);
    __syncthreads();
    int n = blockIdx.x * blockDim.x + threadIdx.x;
    if (n >= N) return;
    float xr[FIN];
#pragma unroll
    for (int i = 0; i < FIN; i++) xr[i] = loadf(x, (size_t)n * FIN + i, f32);
    float dv = dinv[n], dv2 = dv * dv;
#pragma unroll
    for (int f = 0; f < H; f++) {
        float s = 0.f;
#pragma unroll
        for (int i = 0; i < FIN; i++) s += xr[i] * sW[i * H + f];
        xw[(size_t)n * H + f]  = s;
        agg[(size_t)n * H + f] = s * dv2;
    }
}
__global__ void k_scatter(const int* __restrict__ src, const int* __restrict__ dst,
                          const float* __restrict__ dinv, const float* __restrict__ xw,
                          float* __restrict__ agg, int E) {
    int t = blockIdx.x * blockDim.x + threadIdx.x;
    int e = t >> 5, f = t & 31;
    if (e >= E) return;
    int s = src[e], d = dst[e];
    float c = dinv[s] * dinv[d];
    atomicAdd(&agg[(size_t)d * H + f], xw[(size_t)s * H + f] * c);
}
__global__ void k_h1xw2o(const void* __restrict__ W2, const void* __restrict__ b1,
                         const float* __restrict__ dinv, const int* __restrict__ flag,
                         float* __restrict__ aggio, float* __restrict__ xw2, int N) {
    __shared__ float sW[H * H];
    __shared__ float sb[H];
    int f32 = flag[0];
    for (int i = threadIdx.x; i < H * H; i += blockDim.x) sW[i] = loadf(W2, i, f32);
    if (threadIdx.x < H) sb[threadIdx.x] = loadf(b1, threadIdx.x, f32);
    __syncthreads();
    int n = blockIdx.x * blockDim.x + threadIdx.x;
    if (n >= N) return;
    float hr[H];
#pragma unroll
    for (int f = 0; f < H; f++) {
        float v = aggio[(size_t)n * H + f] + sb[f];
        hr[f] = v > 0.f ? v : 0.f;
    }
    float dv = dinv[n], dv2 = dv * dv;
#pragma unroll
    for (int f = 0; f < H; f++) {
        float s = 0.f;
#pragma unroll
        for (int i = 0; i < H; i++) s += hr[i] * sW[i * H + f];
        xw2[(size_t)n * H + f]   = s;
        aggio[(size_t)n * H + f] = s * dv2;
    }
}

// ---------- output heads ----------

__global__ void k_reg(const float* __restrict__ pooled, const float* __restrict__ cnt,
                      const void* __restrict__ Wr, const void* __restrict__ br,
                      const int* __restrict__ flag, void* __restrict__ out, int G) {
    int f32 = flag[0];
    int g = blockIdx.x * blockDim.x + threadIdx.x;
    if (g >= G) return;
    float c = cnt[g];
    c = c > 1.f ? c : 1.f;
    float s = 0.f;
#pragma unroll
    for (int i = 0; i < H; i++) s += pooled[(size_t)g * H + i] * loadf(Wr, i, f32);
    storef(out, g, s / c + loadf(br, 0, f32), f32);
}

__global__ void k_bil(const int* __restrict__ srcA, const int* __restrict__ dstA,
                      const unsigned* __restrict__ gb32, const unsigned* __restrict__ hb32,
                      const void* __restrict__ bbil, const int* __restrict__ flag,
                      void* __restrict__ out, int G, int EA) {
    int f32 = flag[0];
    int e = blockIdx.x * blockDim.x + threadIdx.x;
    if (e >= EA) return;
    int s = srcA[e], d = dstA[e];
    const uint4* gp = (const uint4*)(gb32 + (size_t)s * (H / 2));
    const uint4* hp = (const uint4*)(hb32 + (size_t)d * (H / 2));
    float acc = 0.f;
#pragma unroll
    for (int k = 0; k < 4; k++) {
        uint4 a = gp[k], b = hp[k];
        acc += f_lo(a.x) * f_lo(b.x) + f_hi(a.x) * f_hi(b.x);
        acc += f_lo(a.y) * f_lo(b.y) + f_hi(a.y) * f_hi(b.y);
        acc += f_lo(a.z) * f_lo(b.z) + f_hi(a.z) * f_hi(b.z);
        acc += f_lo(a.w) * f_lo(b.w) + f_hi(a.w) * f_hi(b.w);
    }
    storef(out, (size_t)G + e, acc + loadf(bbil, 0, f32), f32);
}

extern "C" void kernel_launch(void* const* d_in, const int* in_sizes, int n_in,
                              void* d_out, int out_size, void* d_ws, size_t ws_size,
                              hipStream_t stream) {
    const void* x     = d_in[0];
    const int*  ei    = (const int*)d_in[1];
    const int*  eia   = (const int*)d_in[2];
    const int*  batch = (const int*)d_in[3];
    const void* W1    = d_in[4];
    const void* b1    = d_in[5];
    const void* W2    = d_in[6];
    const void* b2    = d_in[7];
    const void* Wr    = d_in[8];
    const void* br    = d_in[9];
    const void* Wbil  = d_in[10];
    const void* bbil  = d_in[11];

    const int N  = in_sizes[0] / FIN;
    const int E  = in_sizes[1] / 2;
    const int EA = in_sizes[2] / 2;
    const int G  = out_size - EA;

    // float region: flag[16] | dinv[N] | A[N*H] | B[N*H] | pooled[G*H] | cnt[G]
    float* ws     = (float*)d_ws;
    int*   flag   = (int*)ws;
    float* dinv   = ws + 16;
    float* A      = dinv + N;
    float* B      = A + (size_t)N * H;
    float* pooled = B + (size_t)N * H;
    float* cnt    = pooled + (size_t)G * H;
    float* fend   = cnt + G;

    // bf16 tables live in A: xsb (build phase) then hb/gb (tail)
    unsigned* xsb  = (unsigned*)A;
    unsigned* hb32 = (unsigned*)A;
    unsigned* gb32 = hb32 + (size_t)N * (H / 2);

    // Tier A / A2 int region: deg[N] | csr_pad[N*PADW] | bincur[NB] | binbuf[NB*BINCAP]
    int* degA   = (int*)fend;
    int* csrA   = degA + N;
    int* bincur = csrA + (size_t)N * PADW;
    unsigned* binbuf = (unsigned*)(bincur + NB);   // own region: no aliasing with A
    size_t needA  = (size_t)((char*)bincur - (char*)d_ws);
    size_t needA2 = (size_t)((char*)(binbuf + (size_t)NB * BINCAP) - (char*)d_ws);
    // Tier B int region
    const int B1 = (N + SCAN_CHUNK - 1) / SCAN_CHUNK;
    int* deg_i     = (int*)fend;
    int* curB      = deg_i + N;
    int* row_ptr   = curB + N;
    int* chunk_off = row_ptr + N + 1;
    int* csrB      = chunk_off + B1 + 1;
    size_t needB = (size_t)((char*)(csrB + E) - (char*)d_ws);

    const int npb = (N + NB - 1) / NB;
    const bool tierA2 = (ws_size >= needA2) && (npb <= NPBMAX) && (N <= (1 << 22));
    const bool tierA  = !tierA2 && (ws_size >= needA);
    const bool tierB  = !tierA2 && !tierA && (ws_size >= needB) && (B1 <= 1024);

    const int* src  = ei;
    const int* dst  = ei + E;
    const int* srcA = eia;
    const int* dstA = eia + EA;

    const int TB = 256;
    int ggrid16 = (int)(((long)N * 16 + TB - 1) / TB);
    int ggrid32 = (int)(((long)N * 32 + TB - 1) / TB);
    int ngrid   = (N + TB - 1) / TB;
    unsigned* xsb2 = xsb;
    float2* aggv = (float2*)B;

    if (tierA2) {
        // k_init: dtype flag + zero pooled/cnt + zero bincur (replaces 2 memsets)
        k_init<<<1, TB, 0, stream>>>(x, 1024, flag, pooled, G * H + G, bincur);
        int nblk1 = (E + CHUNK - 1) / CHUNK;
        k_p1<<<nblk1, 1024, 0, stream>>>(src, dst, bincur, binbuf, E, npb);
        k_p2x<<<NB, TB, 0, stream>>>(bincur, binbuf, x, W1, flag, csrA, degA, dinv, xsb, N, npb);
        k_gatherpb<<<ggrid16, TB, 0, stream>>>(degA, csrA, dinv, xsb, aggv, N);
        k_h1xw2v<<<ggrid16, TB, 0, stream>>>(W2, b1, dinv, flag, aggv, xsb2, N);
        k_gatherpb<<<ggrid16, TB, 0, stream>>>(degA, csrA, dinv, xsb2, aggv, N);
    } else if (tierA) {
        k_init<<<1, TB, 0, stream>>>(x, 1024, flag, pooled, G * H + G, bincur);
        hipMemsetAsync(degA, 0, (size_t)N * sizeof(int), stream);
        k_fillp<<<(E + TB - 1) / TB, TB, 0, stream>>>(src, dst, degA, csrA, E);
        k_dinvi<<<ngrid, TB, 0, stream>>>(degA, dinv, N);
        k_xw1v<<<ggrid16, TB, 0, stream>>>(x, W1, dinv, flag, xsb, N);
        k_gatherpb<<<ggrid16, TB, 0, stream>>>(degA, csrA, dinv, xsb, aggv, N);
        k_h1xw2v<<<ggrid16, TB, 0, stream>>>(W2, b1, dinv, flag, aggv, xsb2, N);
        k_gatherpb<<<ggrid16, TB, 0, stream>>>(degA, csrA, dinv, xsb2, aggv, N);
    } else if (tierB) {
        k_init<<<1, TB, 0, stream>>>(x, 1024, flag, pooled, G * H + G, (int*)chunk_off);
        hipMemsetAsync(deg_i, 0, (size_t)N * sizeof(int), stream);
        k_degi<<<(E + TB - 1) / TB, TB, 0, stream>>>(dst, deg_i, E);
        k_dinvi<<<ngrid, TB, 0, stream>>>(deg_i, dinv, N);
        k_scan1<<<B1, TB, 0, stream>>>(deg_i, chunk_off, N);
        k_scan2<<<1, TB, 0, stream>>>(chunk_off, chunk_off, B1);
        k_scan3<<<B1, TB, 0, stream>>>(deg_i, chunk_off, row_ptr, curB, N, E);
        k_fill<<<(E + TB - 1) / TB, TB, 0, stream>>>(src, dst, curB, csrB, E);
        k_xw1n<<<ngrid, TB, 0, stream>>>(x, W1, dinv, flag, A, N);
        k_gather<<<ggrid32, TB, 0, stream>>>(row_ptr, csrB, dinv, A, B, N);
        k_h1xw2n<<<ngrid, TB, 0, stream>>>(W2, b1, dinv, flag, B, A, N);
        k_gather<<<ggrid32, TB, 0, stream>>>(row_ptr, csrB, dinv, A, B, N);
    } else {
        k_init<<<1, TB, 0, stream>>>(x, 1024, flag, pooled, G * H + G, (int*)flag + 4);
        hipMemsetAsync(dinv, 0, (size_t)N * sizeof(float), stream);
        k_degf<<<(E + TB - 1) / TB, TB, 0, stream>>>(dst, dinv, E);
        k_dinvf<<<ngrid, TB, 0, stream>>>(dinv, N);
        k_xw1o<<<ngrid, TB, 0, stream>>>(x, W1, dinv, flag, A, B, N);
        long tot = (long)E * 32;
        int sgrid = (int)((tot + TB - 1) / TB);
        k_scatter<<<sgrid, TB, 0, stream>>>(src, dst, dinv, A, B, E);
        k_h1xw2o<<<ngrid, TB, 0, stream>>>(W2, b1, dinv, flag, B, A, N);
        k_scatter<<<sgrid, TB, 0, stream>>>(src, dst, dinv, A, B, E);
    }

    k_pool<<<ngrid, TB, 0, stream>>>(b2, batch, flag, B, pooled, cnt, N);
    k_hb<<<ggrid16, TB, 0, stream>>>(b2, Wbil, flag, aggv, hb32, gb32, N);
    k_reg<<<(G + TB - 1) / TB, TB, 0, stream>>>(pooled, cnt, Wr, br, flag, d_out, G);
    k_bil<<<(EA + TB - 1) / TB, TB, 0, stream>>>(srcA, dstA, gb32, hb32, bbil, flag, d_out, G, EA);
}

// Round 14
// 289.879 us; speedup vs baseline: 1.0430x; 1.0430x over previous
//
#include <hip/hip_runtime.h>
#include <hip/hip_bf16.h>
#include <string.h>

typedef __hip_bfloat16 bf16;

#define FIN 16
#define H   32
#define PADW 64
#define NB  512
#define BINCAP 4096
#define NPBMAX 200
#define PSTRIDE 65
#define CHUNK 8192
#define SCAN_CHUNK 1024
#define MAXSEG 64

__device__ __forceinline__ float b2f(bf16 v) { return __bfloat162float(v); }

__device__ __forceinline__ float loadf(const void* p, size_t i, int f32) {
    return f32 ? ((const float*)p)[i] : b2f(((const bf16*)p)[i]);
}
__device__ __forceinline__ void storef(void* p, size_t i, float v, int f32) {
    if (f32) ((float*)p)[i] = v;
    else     ((bf16*)p)[i] = __float2bfloat16(v);
}

__device__ __forceinline__ unsigned pack2(float lo, float hi) {
    bf16 a = __float2bfloat16(lo), b = __float2bfloat16(hi);
    unsigned short ua, ub;
    memcpy(&ua, &a, 2); memcpy(&ub, &b, 2);
    return ((unsigned)ub << 16) | (unsigned)ua;
}
__device__ __forceinline__ float f_lo(unsigned u) {
    union { unsigned i; float f; } v; v.i = u << 16; return v.f;
}
__device__ __forceinline__ float f_hi(unsigned u) {
    union { unsigned i; float f; } v; v.i = u & 0xffff0000u; return v.f;
}

__global__ void k_detect(const void* __restrict__ x, int nelem, int* __restrict__ flag) {
    __shared__ int cnt;
    if (threadIdx.x == 0) cnt = 0;
    __syncthreads();
    int bad = 0;
    const bf16* p = (const bf16*)x;
    for (int i = threadIdx.x; i < nelem; i += blockDim.x) {
        float v = b2f(p[i]);
        float a = fabsf(v);
        if (isnan(v) || a > 1024.f || (v != 0.f && a < 1e-20f)) bad++;
    }
    atomicAdd(&cnt, bad);
    __syncthreads();
    if (threadIdx.x == 0) flag[0] = (cnt > 64) ? 1 : 0;
}

// ---------- Tier A2: two-phase binned padded-CSR build ----------
// 1024 threads/block (8 edges/thread/phase) for occupancy; 4 sub-histograms
// cut LDS-atomic contention + bank conflicts in the count phase.
__global__ void __launch_bounds__(1024) k_p1(
        const int* __restrict__ src, const int* __restrict__ dst,
        int* __restrict__ bincur, unsigned* __restrict__ binbuf,
        int E, int npb) {
    __shared__ int hcnt[4][NB];   // 8 KB
    __shared__ int hbase[NB];
    __shared__ int scur[NB];
    int tid = threadIdx.x;
    int grp = tid >> 8;
    int e0 = blockIdx.x * CHUNK;
    int nE = E - e0;
    if (nE > CHUNK) nE = CHUNK;
    for (int i = tid; i < 4 * NB; i += blockDim.x) ((int*)hcnt)[i] = 0;
    __syncthreads();
    for (int i = tid; i < nE; i += blockDim.x)
        atomicAdd(&hcnt[grp][dst[e0 + i] / npb], 1);
    __syncthreads();
    for (int i = tid; i < NB; i += blockDim.x) {
        int c = hcnt[0][i] + hcnt[1][i] + hcnt[2][i] + hcnt[3][i];
        hbase[i] = c ? atomicAdd(&bincur[i], c) : 0;
        scur[i] = 0;
    }
    __syncthreads();
    for (int i = tid; i < nE; i += blockDim.x) {
        int d = dst[e0 + i];
        int bin = d / npb;
        int pos = hbase[bin] + atomicAdd(&scur[bin], 1);
        if (pos < BINCAP)
            binbuf[(size_t)bin * BINCAP + pos] =
                ((unsigned)src[e0 + i] << 10) | (unsigned)(d - bin * npb);
    }
}

// stride-65 psr rows: LDS bank = (loc+pos)%32 -> spread
__global__ void __launch_bounds__(256) k_p2(
        const int* __restrict__ bincur, const unsigned* __restrict__ binbuf,
        int* __restrict__ csr, int* __restrict__ deg, float* __restrict__ dinv,
        int N, int npb) {
    __shared__ int cur[NPBMAX];
    __shared__ int psr[NPBMAX * PSTRIDE];   // ~52 KB
    int b = blockIdx.x;
    int base = b * npb;
    int nn = N - base;
    if (nn > npb) nn = npb;
    if (nn < 0) nn = 0;
    for (int i = threadIdx.x; i < nn; i += blockDim.x) cur[i] = 0;
    __syncthreads();
    int cnt = bincur[b];
    if (cnt > BINCAP) cnt = BINCAP;
    const unsigned* buf = binbuf + (size_t)b * BINCAP;
    for (int j = threadIdx.x; j < cnt; j += blockDim.x) {
        unsigned p = buf[j];
        int loc = (int)(p & 1023u);
        int s = (int)(p >> 10);
        int pos = atomicAdd(&cur[loc], 1);
        if (pos < PADW) psr[loc * PSTRIDE + pos] = s;
    }
    __syncthreads();
    int tot = nn * PADW;
    for (int idx = threadIdx.x; idx < tot; idx += blockDim.x) {
        int i = idx >> 6, p = idx & 63;
        csr[((size_t)(base + i) << 6) + p] = psr[i * PSTRIDE + p];
    }
    for (int i = threadIdx.x; i < nn; i += blockDim.x) {
        int dg = cur[i];
        deg[base + i] = dg;
        dinv[base + i] = rsqrtf((float)dg + 1.0f);
    }
}

// ---------- Tier A: direct padded CSR (fallback build) ----------

__global__ void k_fillp(const int* __restrict__ src, const int* __restrict__ dst,
                        int* __restrict__ cursor, int* __restrict__ csr, int E) {
    int e = blockIdx.x * blockDim.x + threadIdx.x;
    if (e >= E) return;
    int d = dst[e];
    int pos = atomicAdd(&cursor[d], 1);
    if (pos < PADW) csr[((size_t)d << 6) + pos] = src[e];
}

__global__ void k_dinvi(const int* __restrict__ deg, float* __restrict__ dinv, int N) {
    int t = blockIdx.x * blockDim.x + threadIdx.x;
    if (t < N) dinv[t] = rsqrtf((float)deg[t] + 1.0f);
}

// bf16-table gather: 16 lanes/node, lane j owns packed pair (2j,2j+1).
__global__ void k_gatherpb(const int* __restrict__ deg, const int* __restrict__ csr,
                           const float* __restrict__ dinv, const unsigned* __restrict__ xsb,
                           float2* __restrict__ agg, int N) {
    int t = blockIdx.x * blockDim.x + threadIdx.x;
    int d = t >> 4, j = t & 15;
    if (d >= N) return;
    int len = deg[d];
    if (len > PADW) len = PADW;
    const int* lst = csr + ((size_t)d << 6);
    unsigned u = xsb[(size_t)d * 16 + j];      // self-loop
    float a0 = f_lo(u), a1 = f_hi(u);
    float b0 = 0.f, b1 = 0.f;
    int k = 0;
    for (; k + 1 < len; k += 2) {
        int s0 = lst[k], s1 = lst[k + 1];
        unsigned u0 = xsb[(size_t)s0 * 16 + j];
        unsigned u1 = xsb[(size_t)s1 * 16 + j];
        a0 += f_lo(u0); a1 += f_hi(u0);
        b0 += f_lo(u1); b1 += f_hi(u1);
    }
    if (k < len) {
        unsigned u2 = xsb[(size_t)lst[k] * 16 + j];
        a0 += f_lo(u2); a1 += f_hi(u2);
    }
    float dv = dinv[d];
    agg[(size_t)d * 16 + j] = make_float2((a0 + b0) * dv, (a1 + b1) * dv);
}

// ---------- wave-cooperative dense kernels (16 lanes/node) ----------

__global__ void __launch_bounds__(256) k_xw1v(
        const void* __restrict__ x, const void* __restrict__ W1,
        const float* __restrict__ dinv, const int* __restrict__ flag,
        unsigned* __restrict__ xsb, int N) {
    __shared__ float sW[FIN * H];
    __shared__ float sxx[16 * 17];
    int f32 = flag[0];
    for (int i = threadIdx.x; i < FIN * H; i += blockDim.x) sW[i] = loadf(W1, i, f32);
    __syncthreads();
    int t = blockIdx.x * blockDim.x + threadIdx.x;
    int n = t >> 4, j = t & 15, g = threadIdx.x >> 4;
    if (n < N) sxx[g * 17 + j] = loadf(x, (size_t)n * FIN + j, f32);
    __syncthreads();
    if (n >= N) return;
    float dv = dinv[n];
    float s0 = 0.f, s1 = 0.f;
    const float* xp = &sxx[g * 17];
#pragma unroll
    for (int i = 0; i < FIN; i++) {
        float xv = xp[i];
        s0 += xv * sW[i * H + 2 * j];
        s1 += xv * sW[i * H + 2 * j + 1];
    }
    xsb[(size_t)n * 16 + j] = pack2(s0 * dv, s1 * dv);
}

__global__ void __launch_bounds__(256) k_h1xw2v(
        const void* __restrict__ W2, const void* __restrict__ b1,
        const float* __restrict__ dinv, const int* __restrict__ flag,
        const float2* __restrict__ aggv, unsigned* __restrict__ xsb2, int N) {
    __shared__ float sW[H * H];
    __shared__ float sb[H];
    __shared__ float shh[16 * 33];
    int f32 = flag[0];
    for (int i = threadIdx.x; i < H * H; i += blockDim.x) sW[i] = loadf(W2, i, f32);
    if (threadIdx.x < H) sb[threadIdx.x] = loadf(b1, threadIdx.x, f32);
    __syncthreads();
    int t = blockIdx.x * blockDim.x + threadIdx.x;
    int n = t >> 4, j = t & 15, g = threadIdx.x >> 4;
    if (n < N) {
        float2 a = aggv[(size_t)n * 16 + j];
        float v0 = a.x + sb[2 * j], v1 = a.y + sb[2 * j + 1];
        shh[g * 33 + 2 * j]     = v0 > 0.f ? v0 : 0.f;
        shh[g * 33 + 2 * j + 1] = v1 > 0.f ? v1 : 0.f;
    }
    __syncthreads();
    if (n >= N) return;
    float dv = dinv[n];
    float s0 = 0.f, s1 = 0.f;
    const float* hp = &shh[g * 33];
#pragma unroll
    for (int i = 0; i < H; i++) {
        float hv = hp[i];
        s0 += hv * sW[i * H + 2 * j];
        s1 += hv * sW[i * H + 2 * j + 1];
    }
    xsb2[(size_t)n * 16 + j] = pack2(s0 * dv, s1 * dv);
}

// h = agg2 + b2; hb = bf16(h); gb = bf16(h @ Wbil)   (16 lanes/node)
__global__ void __launch_bounds__(256) k_hb(
        const void* __restrict__ b2v, const void* __restrict__ Wbil,
        const int* __restrict__ flag, const float2* __restrict__ aggv,
        unsigned* __restrict__ hb32, unsigned* __restrict__ gb32, int N) {
    __shared__ float sW[H * H];
    __shared__ float sb[H];
    __shared__ float shh[16 * 33];
    int f32 = flag[0];
    for (int i = threadIdx.x; i < H * H; i += blockDim.x) sW[i] = loadf(Wbil, i, f32);
    if (threadIdx.x < H) sb[threadIdx.x] = loadf(b2v, threadIdx.x, f32);
    __syncthreads();
    int t = blockIdx.x * blockDim.x + threadIdx.x;
    int n = t >> 4, j = t & 15, g = threadIdx.x >> 4;
    if (n < N) {
        float2 a = aggv[(size_t)n * 16 + j];
        float v0 = a.x + sb[2 * j], v1 = a.y + sb[2 * j + 1];
        shh[g * 33 + 2 * j]     = v0;
        shh[g * 33 + 2 * j + 1] = v1;
        hb32[(size_t)n * 16 + j] = pack2(v0, v1);
    }
    __syncthreads();
    if (n >= N) return;
    float s0 = 0.f, s1 = 0.f;
    const float* hp = &shh[g * 33];
#pragma unroll
    for (int i = 0; i < H; i++) {
        float hv = hp[i];
        s0 += hv * sW[i * H + 2 * j];
        s1 += hv * sW[i * H + 2 * j + 1];
    }
    gb32[(size_t)n * 16 + j] = pack2(s0, s1);
}

// parallel segmented mean-pool
__global__ void __launch_bounds__(256) k_pool(
        const void* __restrict__ b2v, const int* __restrict__ batch,
        const int* __restrict__ flag, const float* __restrict__ aggB,
        float* __restrict__ pooled, float* __restrict__ cnt, int N) {
    __shared__ float sb[H];
    __shared__ int   sg[256];
    __shared__ float spool[MAXSEG * H];
    __shared__ float scnt[MAXSEG];
    int f32 = flag[0];
    if (threadIdx.x < H) sb[threadIdx.x] = loadf(b2v, threadIdx.x, f32);
    int blk0 = blockIdx.x * blockDim.x;
    int nvalid = N - blk0;
    if (nvalid > (int)blockDim.x) nvalid = blockDim.x;
    if ((int)threadIdx.x < nvalid) sg[threadIdx.x] = batch[blk0 + threadIdx.x];
    __syncthreads();
    int g0 = sg[0];
    int nseg = sg[nvalid - 1] - g0 + 1;
    int f = threadIdx.x & 31, k = threadIdx.x >> 5;
    if (nseg <= MAXSEG) {
        for (int i = threadIdx.x; i < nseg * H; i += blockDim.x) spool[i] = 0.f;
        for (int i = threadIdx.x; i < nseg; i += blockDim.x) scnt[i] = 0.f;
        __syncthreads();
        for (int r = k; r < nvalid; r += 8) {
            float v = aggB[(size_t)(blk0 + r) * H + f] + sb[f];
            int gl = sg[r] - g0;
            atomicAdd(&spool[gl * H + f], v);
            if (f == 0) atomicAdd(&scnt[gl], 1.f);
        }
        __syncthreads();
        for (int i = threadIdx.x; i < nseg * H; i += blockDim.x)
            atomicAdd(&pooled[(size_t)(g0 + (i >> 5)) * H + (i & 31)], spool[i]);
        for (int i = threadIdx.x; i < nseg; i += blockDim.x)
            atomicAdd(&cnt[g0 + i], scnt[i]);
    } else {
        for (int r = k; r < nvalid; r += 8) {
            float v = aggB[(size_t)(blk0 + r) * H + f] + sb[f];
            atomicAdd(&pooled[(size_t)sg[r] * H + f], v);
            if (f == 0) atomicAdd(&cnt[sg[r]], 1.f);
        }
    }
}

// ---------- Tier B: compact CSR via scans (fp32 path) ----------

__global__ void k_degi(const int* __restrict__ dst, int* __restrict__ deg, int E) {
    int t = blockIdx.x * blockDim.x + threadIdx.x;
    if (t < E) atomicAdd(&deg[dst[t]], 1);
}

__global__ void k_scan1(const int* __restrict__ deg, int* __restrict__ partials, int N) {
    __shared__ int sd[256];
    int base = blockIdx.x * SCAN_CHUNK + threadIdx.x * 4;
    int s = 0;
#pragma unroll
    for (int k = 0; k < 4; k++) { int i = base + k; s += (i < N) ? deg[i] : 0; }
    sd[threadIdx.x] = s;
    __syncthreads();
    for (int off = 128; off > 0; off >>= 1) {
        if (threadIdx.x < off) sd[threadIdx.x] += sd[threadIdx.x + off];
        __syncthreads();
    }
    if (threadIdx.x == 0) partials[blockIdx.x] = sd[0];
}

__global__ void k_scan2(const int* __restrict__ partials, int* __restrict__ chunk_off, int B1) {
    __shared__ int sd[256];
    int t = threadIdx.x;
    int lv[4];
    int s = 0;
#pragma unroll
    for (int k = 0; k < 4; k++) { int i = t * 4 + k; lv[k] = (i < B1) ? partials[i] : 0; s += lv[k]; }
    sd[t] = s;
    __syncthreads();
    int inc = s;
    for (int off = 1; off < 256; off <<= 1) {
        int v = (t >= off) ? sd[t - off] : 0;
        __syncthreads();
        sd[t] += v;
        __syncthreads();
    }
    int run = sd[t] - inc;
#pragma unroll
    for (int k = 0; k < 4; k++) { int i = t * 4 + k; if (i < B1) chunk_off[i] = run; run += lv[k]; }
    if (t == 255) chunk_off[B1] = run;
}

__global__ void k_scan3(const int* __restrict__ deg, const int* __restrict__ chunk_off,
                        int* __restrict__ row_ptr, int* __restrict__ cursor,
                        int N, int E) {
    __shared__ int sd[256];
    int t = threadIdx.x;
    int base = blockIdx.x * SCAN_CHUNK + t * 4;
    int lv[4];
    int s = 0;
#pragma unroll
    for (int k = 0; k < 4; k++) { int i = base + k; lv[k] = (i < N) ? deg[i] : 0; s += lv[k]; }
    sd[t] = s;
    __syncthreads();
    int inc = s;
    for (int off = 1; off < 256; off <<= 1) {
        int v = (t >= off) ? sd[t - off] : 0;
        __syncthreads();
        sd[t] += v;
        __syncthreads();
    }
    int run = chunk_off[blockIdx.x] + sd[t] - inc;
#pragma unroll
    for (int k = 0; k < 4; k++) {
        int i = base + k;
        if (i < N) { row_ptr[i] = run; cursor[i] = run; }
        run += lv[k];
    }
    if (blockIdx.x == 0 && t == 0) row_ptr[N] = E;
}

__global__ void k_fill(const int* __restrict__ src, const int* __restrict__ dst,
                       int* __restrict__ cursor, int* __restrict__ csr, int E) {
    int e = blockIdx.x * blockDim.x + threadIdx.x;
    if (e >= E) return;
    int pos = atomicAdd(&cursor[dst[e]], 1);
    csr[pos] = src[e];
}

__global__ void k_gather(const int* __restrict__ row_ptr, const int* __restrict__ csr,
                         const float* __restrict__ dinv, const float* __restrict__ xs,
                         float* __restrict__ agg, int N) {
    int t = blockIdx.x * blockDim.x + threadIdx.x;
    int d = t >> 5, f = t & 31;
    if (d >= N) return;
    int beg = row_ptr[d], end = row_ptr[d + 1];
    float acc  = xs[(size_t)d * H + f];
    float acc2 = 0.f;
    int j = beg;
    for (; j + 1 < end; j += 2) {
        int s0 = csr[j], s1 = csr[j + 1];
        acc  += xs[(size_t)s0 * H + f];
        acc2 += xs[(size_t)s1 * H + f];
    }
    if (j < end) acc += xs[(size_t)csr[j] * H + f];
    agg[(size_t)d * H + f] = (acc + acc2) * dinv[d];
}

__global__ void k_xw1n(const void* __restrict__ x, const void* __restrict__ W1,
                       const float* __restrict__ dinv, const int* __restrict__ flag,
                       float* __restrict__ xs, int N) {
    __shared__ float sW[FIN * H];
    int f32 = flag[0];
    for (int i = threadIdx.x; i < FIN * H; i += blockDim.x) sW[i] = loadf(W1, i, f32);
    __syncthreads();
    int n = blockIdx.x * blockDim.x + threadIdx.x;
    if (n >= N) return;
    float xr[FIN];
#pragma unroll
    for (int i = 0; i < FIN; i++) xr[i] = loadf(x, (size_t)n * FIN + i, f32);
    float dv = dinv[n];
#pragma unroll
    for (int f = 0; f < H; f++) {
        float s = 0.f;
#pragma unroll
        for (int i = 0; i < FIN; i++) s += xr[i] * sW[i * H + f];
        xs[(size_t)n * H + f] = s * dv;
    }
}

__global__ void k_h1xw2n(const void* __restrict__ W2, const void* __restrict__ b1,
                         const float* __restrict__ dinv, const int* __restrict__ flag,
                         const float* __restrict__ agg, float* __restrict__ xs2, int N) {
    __shared__ float sW[H * H];
    __shared__ float sb[H];
    int f32 = flag[0];
    for (int i = threadIdx.x; i < H * H; i += blockDim.x) sW[i] = loadf(W2, i, f32);
    if (threadIdx.x < H) sb[threadIdx.x] = loadf(b1, threadIdx.x, f32);
    __syncthreads();
    int n = blockIdx.x * blockDim.x + threadIdx.x;
    if (n >= N) return;
    float hr[H];
#pragma unroll
    for (int f = 0; f < H; f++) {
        float v = agg[(size_t)n * H + f] + sb[f];
        hr[f] = v > 0.f ? v : 0.f;
    }
    float dv = dinv[n];
#pragma unroll
    for (int f = 0; f < H; f++) {
        float s = 0.f;
#pragma unroll
        for (int i = 0; i < H; i++) s += hr[i] * sW[i * H + f];
        xs2[(size_t)n * H + f] = s * dv;
    }
}

// ---------- Tier C fallback: scatter path ----------

__global__ void k_degf(const int* __restrict__ dst, float* __restrict__ deg, int E) {
    int t = blockIdx.x * blockDim.x + threadIdx.x;
    if (t < E) atomicAdd(&deg[dst[t]], 1.0f);
}
__global__ void k_dinvf(float* __restrict__ deg, int N) {
    int t = blockIdx.x * blockDim.x + threadIdx.x;
    if (t < N) deg[t] = rsqrtf(deg[t] + 1.0f);
}
__global__ void k_xw1o(const void* __restrict__ x, const void* __restrict__ W1,
                       const float* __restrict__ dinv, const int* __restrict__ flag,
                       float* __restrict__ xw, float* __restrict__ agg, int N) {
    __shared__ float sW[FIN * H];
    int f32 = flag[0];
    for (int i = threadIdx.x; i < FIN * H; i += blockDim.x) sW[i] = loadf(W1, i, f32);
    __syncthreads();
    int n = blockIdx.x * blockDim.x + threadIdx.x;
    if (n >= N) return;
    float xr[FIN];
#pragma unroll
    for (int i = 0; i < FIN; i++) xr[i] = loadf(x, (size_t)n * FIN + i, f32);
    float dv = dinv[n], dv2 = dv * dv;
#pragma unroll
    for (int f = 0; f < H; f++) {
        float s = 0.f;
#pragma unroll
        for (int i = 0; i < FIN; i++) s += xr[i] * sW[i * H + f];
        xw[(size_t)n * H + f]  = s;
        agg[(size_t)n * H + f] = s * dv2;
    }
}
__global__ void k_scatter(const int* __restrict__ src, const int* __restrict__ dst,
                          const float* __restrict__ dinv, const float* __restrict__ xw,
                          float* __restrict__ agg, int E) {
    int t = blockIdx.x * blockDim.x + threadIdx.x;
    int e = t >> 5, f = t & 31;
    if (e >= E) return;
    int s = src[e], d = dst[e];
    float c = dinv[s] * dinv[d];
    atomicAdd(&agg[(size_t)d * H + f], xw[(size_t)s * H + f] * c);
}
__global__ void k_h1xw2o(const void* __restrict__ W2, const void* __restrict__ b1,
                         const float* __restrict__ dinv, const int* __restrict__ flag,
                         float* __restrict__ aggio, float* __restrict__ xw2, int N) {
    __shared__ float sW[H * H];
    __shared__ float sb[H];
    int f32 = flag[0];
    for (int i = threadIdx.x; i < H * H; i += blockDim.x) sW[i] = loadf(W2, i, f32);
    if (threadIdx.x < H) sb[threadIdx.x] = loadf(b1, threadIdx.x, f32);
    __syncthreads();
    int n = blockIdx.x * blockDim.x + threadIdx.x;
    if (n >= N) return;
    float hr[H];
#pragma unroll
    for (int f = 0; f < H; f++) {
        float v = aggio[(size_t)n * H + f] + sb[f];
        hr[f] = v > 0.f ? v : 0.f;
    }
    float dv = dinv[n], dv2 = dv * dv;
#pragma unroll
    for (int f = 0; f < H; f++) {
        float s = 0.f;
#pragma unroll
        for (int i = 0; i < H; i++) s += hr[i] * sW[i * H + f];
        xw2[(size_t)n * H + f]   = s;
        aggio[(size_t)n * H + f] = s * dv2;
    }
}

// ---------- output heads ----------

__global__ void k_reg(const float* __restrict__ pooled, const float* __restrict__ cnt,
                      const void* __restrict__ Wr, const void* __restrict__ br,
                      const int* __restrict__ flag, void* __restrict__ out, int G) {
    int f32 = flag[0];
    int g = blockIdx.x * blockDim.x + threadIdx.x;
    if (g >= G) return;
    float c = cnt[g];
    c = c > 1.f ? c : 1.f;
    float s = 0.f;
#pragma unroll
    for (int i = 0; i < H; i++) s += pooled[(size_t)g * H + i] * loadf(Wr, i, f32);
    storef(out, g, s / c + loadf(br, 0, f32), f32);
}

__global__ void k_bil(const int* __restrict__ srcA, const int* __restrict__ dstA,
                      const unsigned* __restrict__ gb32, const unsigned* __restrict__ hb32,
                      const void* __restrict__ bbil, const int* __restrict__ flag,
                      void* __restrict__ out, int G, int EA) {
    int f32 = flag[0];
    int e = blockIdx.x * blockDim.x + threadIdx.x;
    if (e >= EA) return;
    int s = srcA[e], d = dstA[e];
    const uint4* gp = (const uint4*)(gb32 + (size_t)s * (H / 2));
    const uint4* hp = (const uint4*)(hb32 + (size_t)d * (H / 2));
    float acc = 0.f;
#pragma unroll
    for (int k = 0; k < 4; k++) {
        uint4 a = gp[k], b = hp[k];
        acc += f_lo(a.x) * f_lo(b.x) + f_hi(a.x) * f_hi(b.x);
        acc += f_lo(a.y) * f_lo(b.y) + f_hi(a.y) * f_hi(b.y);
        acc += f_lo(a.z) * f_lo(b.z) + f_hi(a.z) * f_hi(b.z);
        acc += f_lo(a.w) * f_lo(b.w) + f_hi(a.w) * f_hi(b.w);
    }
    storef(out, (size_t)G + e, acc + loadf(bbil, 0, f32), f32);
}

extern "C" void kernel_launch(void* const* d_in, const int* in_sizes, int n_in,
                              void* d_out, int out_size, void* d_ws, size_t ws_size,
                              hipStream_t stream) {
    const void* x     = d_in[0];
    const int*  ei    = (const int*)d_in[1];
    const int*  eia   = (const int*)d_in[2];
    const int*  batch = (const int*)d_in[3];
    const void* W1    = d_in[4];
    const void* b1    = d_in[5];
    const void* W2    = d_in[6];
    const void* b2    = d_in[7];
    const void* Wr    = d_in[8];
    const void* br    = d_in[9];
    const void* Wbil  = d_in[10];
    const void* bbil  = d_in[11];

    const int N  = in_sizes[0] / FIN;
    const int E  = in_sizes[1] / 2;
    const int EA = in_sizes[2] / 2;
    const int G  = out_size - EA;

    // float region: flag[16] | dinv[N] | A[N*H] | B[N*H] | pooled[G*H] | cnt[G]
    float* ws     = (float*)d_ws;
    int*   flag   = (int*)ws;
    float* dinv   = ws + 16;
    float* A      = dinv + N;
    float* B      = A + (size_t)N * H;
    float* pooled = B + (size_t)N * H;
    float* cnt    = pooled + (size_t)G * H;
    float* fend   = cnt + G;

    // bf16 tables live in A: xsb (build phase) then hb/gb (tail)
    unsigned* xsb  = (unsigned*)A;
    unsigned* hb32 = (unsigned*)A;
    unsigned* gb32 = hb32 + (size_t)N * (H / 2);

    // Tier A / A2 int region: deg[N] | csr_pad[N*PADW] | bincur[NB]
    int* degA   = (int*)fend;
    int* csrA   = degA + N;
    int* bincur = csrA + (size_t)N * PADW;
    size_t needA  = (size_t)((char*)bincur - (char*)d_ws);
    size_t needA2 = (size_t)((char*)(bincur + NB) - (char*)d_ws);
    // Tier B int region
    const int B1 = (N + SCAN_CHUNK - 1) / SCAN_CHUNK;
    int* deg_i     = (int*)fend;
    int* curB      = deg_i + N;
    int* row_ptr   = curB + N;
    int* chunk_off = row_ptr + N + 1;
    int* csrB      = chunk_off + B1 + 1;
    size_t needB = (size_t)((char*)(csrB + E) - (char*)d_ws);

    const int npb = (N + NB - 1) / NB;
    const bool tierA2 = (ws_size >= needA2) && (npb <= NPBMAX) && (N <= (1 << 22)) &&
                        ((size_t)NB * BINCAP <= (size_t)N * H * 2);
    const bool tierA  = !tierA2 && (ws_size >= needA);
    const bool tierB  = !tierA2 && !tierA && (ws_size >= needB) && (B1 <= 1024);

    const int* src  = ei;
    const int* dst  = ei + E;
    const int* srcA = eia;
    const int* dstA = eia + EA;

    const int TB = 256;
    hipMemsetAsync(pooled, 0, ((size_t)G * H + G) * sizeof(float), stream);
    k_detect<<<1, TB, 0, stream>>>(x, 1024, flag);

    int ggrid16 = (int)(((long)N * 16 + TB - 1) / TB);
    int ggrid32 = (int)(((long)N * 32 + TB - 1) / TB);
    int ngrid   = (N + TB - 1) / TB;
    unsigned* xsb2 = xsb;
    float2* aggv = (float2*)B;

    if (tierA2) {
        unsigned* binbuf = (unsigned*)A;
        hipMemsetAsync(bincur, 0, NB * sizeof(int), stream);
        int nblk1 = (E + CHUNK - 1) / CHUNK;
        k_p1<<<nblk1, 1024, 0, stream>>>(src, dst, bincur, binbuf, E, npb);
        k_p2<<<NB, TB, 0, stream>>>(bincur, binbuf, csrA, degA, dinv, N, npb);
        k_xw1v<<<ggrid16, TB, 0, stream>>>(x, W1, dinv, flag, xsb, N);
        k_gatherpb<<<ggrid16, TB, 0, stream>>>(degA, csrA, dinv, xsb, aggv, N);
        k_h1xw2v<<<ggrid16, TB, 0, stream>>>(W2, b1, dinv, flag, aggv, xsb2, N);
        k_gatherpb<<<ggrid16, TB, 0, stream>>>(degA, csrA, dinv, xsb2, aggv, N);
    } else if (tierA) {
        hipMemsetAsync(degA, 0, (size_t)N * sizeof(int), stream);
        k_fillp<<<(E + TB - 1) / TB, TB, 0, stream>>>(src, dst, degA, csrA, E);
        k_dinvi<<<ngrid, TB, 0, stream>>>(degA, dinv, N);
        k_xw1v<<<ggrid16, TB, 0, stream>>>(x, W1, dinv, flag, xsb, N);
        k_gatherpb<<<ggrid16, TB, 0, stream>>>(degA, csrA, dinv, xsb, aggv, N);
        k_h1xw2v<<<ggrid16, TB, 0, stream>>>(W2, b1, dinv, flag, aggv, xsb2, N);
        k_gatherpb<<<ggrid16, TB, 0, stream>>>(degA, csrA, dinv, xsb2, aggv, N);
    } else if (tierB) {
        hipMemsetAsync(deg_i, 0, (size_t)N * sizeof(int), stream);
        k_degi<<<(E + TB - 1) / TB, TB, 0, stream>>>(dst, deg_i, E);
        k_dinvi<<<ngrid, TB, 0, stream>>>(deg_i, dinv, N);
        k_scan1<<<B1, TB, 0, stream>>>(deg_i, chunk_off, N);
        k_scan2<<<1, TB, 0, stream>>>(chunk_off, chunk_off, B1);
        k_scan3<<<B1, TB, 0, stream>>>(deg_i, chunk_off, row_ptr, curB, N, E);
        k_fill<<<(E + TB - 1) / TB, TB, 0, stream>>>(src, dst, curB, csrB, E);
        k_xw1n<<<ngrid, TB, 0, stream>>>(x, W1, dinv, flag, A, N);
        k_gather<<<ggrid32, TB, 0, stream>>>(row_ptr, csrB, dinv, A, B, N);
        k_h1xw2n<<<ngrid, TB, 0, stream>>>(W2, b1, dinv, flag, B, A, N);
        k_gather<<<ggrid32, TB, 0, stream>>>(row_ptr, csrB, dinv, A, B, N);
    } else {
        hipMemsetAsync(dinv, 0, (size_t)N * sizeof(float), stream);
        k_degf<<<(E + TB - 1) / TB, TB, 0, stream>>>(dst, dinv, E);
        k_dinvf<<<ngrid, TB, 0, stream>>>(dinv, N);
        k_xw1o<<<ngrid, TB, 0, stream>>>(x, W1, dinv, flag, A, B, N);
        long tot = (long)E * 32;
        int sgrid = (int)((tot + TB - 1) / TB);
        k_scatter<<<sgrid, TB, 0, stream>>>(src, dst, dinv, A, B, E);
        k_h1xw2o<<<ngrid, TB, 0, stream>>>(W2, b1, dinv, flag, B, A, N);
        k_scatter<<<sgrid, TB, 0, stream>>>(src, dst, dinv, A, B, E);
    }

    k_pool<<<ngrid, TB, 0, stream>>>(b2, batch, flag, B, pooled, cnt, N);
    k_hb<<<ggrid16, TB, 0, stream>>>(b2, Wbil, flag, aggv, hb32, gb32, N);
    k_reg<<<(G + TB - 1) / TB, TB, 0, stream>>>(pooled, cnt, Wr, br, flag, d_out, G);
    k_bil<<<(EA + TB - 1) / TB, TB, 0, stream>>>(srcA, dstA, gb32, hb32, bbil, flag, d_out, G, EA);
}